// Round 16
// baseline (421.727 us; speedup 1.0000x reference)
//
#include <hip/hip_runtime.h>
#include <math.h>

#define B_ 4
#define L_ 1024
#define DM 256
#define DIN 512
#define NST 16
#define DTR 16
#define CHK 128         // number of chunks over L
#define CT (L_ / CHK)   // chunk length = 8

typedef short short8 __attribute__((ext_vector_type(8)));
typedef float float4v __attribute__((ext_vector_type(4)));

__device__ __forceinline__ float softplusf(float x) {
    return (x > 20.f) ? x : log1pf(__expf(x));
}
__device__ __forceinline__ float siluf(float x) {
    return x / (1.f + __expf(-x));
}
__device__ __forceinline__ unsigned short f2bf(float f) {  // RNE bf16
    unsigned int u = __float_as_uint(f);
    u = (u + 0x7fffu + ((u >> 16) & 1u)) >> 16;
    return (unsigned short)u;
}
__device__ __forceinline__ float bf2f(unsigned short u) {
    return __uint_as_float((unsigned int)u << 16);
}

// two-value block reduction (sum) over 256 threads = 4 waves
__device__ __forceinline__ void block_reduce2(float& a, float& q) {
    #pragma unroll
    for (int off = 32; off > 0; off >>= 1) {
        a += __shfl_down(a, off);
        q += __shfl_down(q, off);
    }
    __shared__ float sa[4], sq[4];
    int lane = threadIdx.x & 63, w = threadIdx.x >> 6;
    if (lane == 0) { sa[w] = a; sq[w] = q; }
    __syncthreads();
    a = sa[0] + sa[1] + sa[2] + sa[3];
    q = sq[0] + sq[1] + sq[2] + sq[3];
}

// ---- prologue: weight f2bf + input projection + layer-0 LN ----
__global__ __launch_bounds__(256) void prologue_kernel(
    const float* __restrict__ inw, int na, const float* __restrict__ xpw, int nb,
    const float* __restrict__ opw, int nc,
    unsigned short* __restrict__ oa, unsigned short* __restrict__ ob,
    unsigned short* __restrict__ oc, int nconv,
    const float* __restrict__ x, const float* __restrict__ ipw,
    const float* __restrict__ ipb, const float* __restrict__ lw0,
    const float* __restrict__ lb0, float* __restrict__ h0,
    unsigned short* __restrict__ ln16)
{
    if ((int)blockIdx.x < nconv) {
        int i = blockIdx.x * 256 + threadIdx.x;
        if (i < na) { oa[i] = f2bf(inw[i]); return; }
        int j = i - na;
        if (j < nb) { ob[j] = f2bf(xpw[j]); return; }
        int k = j - nb;
        if (k < nc) oc[k] = f2bf(opw[k]);
        return;
    }
    int row = blockIdx.x - nconv;                 // 0..4095 = b*L + l
    int l = row & (L_ - 1);
    int b = row >> 10;
    int d = threadIdx.x;
    const float* xb = x + (size_t)b * 3 * L_;
    float x0 = xb[l], x1 = xb[L_ + l], x2 = xb[2 * L_ + l];
    float acc = ipb[d];
    acc = fmaf(x0, ipw[d * 3 + 0], acc);
    acc = fmaf(x1, ipw[d * 3 + 1], acc);
    acc = fmaf(x2, ipw[d * 3 + 2], acc);
    float a = acc, q = acc * acc;
    block_reduce2(a, q);
    float mu = a * (1.f / DM);
    float var = q * (1.f / DM) - mu * mu;
    float rs = rsqrtf(var + 1e-5f);
    h0[(size_t)row * DM + d] = acc;
    ln16[(size_t)row * DM + d] = f2bf((acc - mu) * rs * lw0[d] + lb0[d]);
}

// ---- 64x64-tile bf16 MFMA GEMM (in_proj): C(bf16) = A @ W^T ----
__global__ __launch_bounds__(256) void gemm_bt_bf16(
    const unsigned short* __restrict__ A, const unsigned short* __restrict__ W,
    unsigned short* __restrict__ C, int M, int N, int K, int lda)
{
    __shared__ unsigned short As[64][72];
    __shared__ unsigned short Ws[64][72];
    const int tid = threadIdx.x;
    const int wave = tid >> 6;
    const int lane = tid & 63;
    const int m_l = lane & 15;
    const int q = lane >> 4;
    const int m0 = blockIdx.y * 64;
    const int n0 = blockIdx.x * 64;
    const int sr = tid >> 3;
    const int sc = (tid & 7) * 8;

    float4v acc[4];
    #pragma unroll
    for (int j = 0; j < 4; ++j) acc[j] = (float4v)(0.f);

    for (int k0 = 0; k0 < K; k0 += 64) {
        *(short8*)&As[sr][sc]      = *(const short8*)(A + (size_t)(m0 + sr) * lda + k0 + sc);
        *(short8*)&As[sr + 32][sc] = *(const short8*)(A + (size_t)(m0 + sr + 32) * lda + k0 + sc);
        *(short8*)&Ws[sr][sc]      = *(const short8*)(W + (size_t)(n0 + sr) * K + k0 + sc);
        *(short8*)&Ws[sr + 32][sc] = *(const short8*)(W + (size_t)(n0 + sr + 32) * K + k0 + sc);
        __syncthreads();
        #pragma unroll
        for (int kk = 0; kk < 64; kk += 32) {
            short8 a = *(const short8*)&As[wave * 16 + m_l][kk + q * 8];
            #pragma unroll
            for (int j4 = 0; j4 < 4; ++j4) {
                short8 bf = *(const short8*)&Ws[j4 * 16 + m_l][kk + q * 8];
                acc[j4] = __builtin_amdgcn_mfma_f32_16x16x32_bf16(a, bf, acc[j4], 0, 0, 0);
            }
        }
        __syncthreads();
    }
    #pragma unroll
    for (int j4 = 0; j4 < 4; ++j4) {
        int n = n0 + j4 * 16 + m_l;
        #pragma unroll
        for (int reg = 0; reg < 4; ++reg) {
            int m = m0 + wave * 16 + q * 4 + reg;
            C[(size_t)m * N + n] = f2bf(acc[j4][reg]);
        }
    }
}

// ---- fused conv+silu + x_proj GEMM + scan summary (one chunk per block) ----
// CT=8: MFMA A-rows 8..15 are clamped duplicates; their D rows are discarded
// (D rows are row-separable in MFMA, so garbage rows never contaminate kept ones).
__global__ __launch_bounds__(512) void conv_xproj_summary(
    const unsigned short* __restrict__ xz, const float* __restrict__ cw,
    const float* __restrict__ cb, const unsigned short* __restrict__ W,
    const float* __restrict__ A_log, const float* __restrict__ dt_w,
    const float* __restrict__ dt_b,
    float* __restrict__ dbc, float* __restrict__ S, float* __restrict__ H)
{
    __shared__ unsigned short As[CT][520];   // xc bf16, rows t, cols d (+8 pad)
    __shared__ float Dbc[CT][64];            // dbc tile (48 used)
    const int tid = threadIdx.x;             // 0..511, = channel d
    const int d = tid;
    const int c = blockIdx.x;
    const int b = blockIdx.y;
    const int l0 = c * CT;

    // --- conv + silu, rolling 4-tap window; fp32 math on bf16 inputs ---
    float xcr[CT];
    {
        const float w0 = cw[d * 4 + 0], w1 = cw[d * 4 + 1];
        const float w2 = cw[d * 4 + 2], w3 = cw[d * 4 + 3];
        const float cbv = cb[d];
        const unsigned short* xp = xz + ((size_t)(b * L_ + l0)) * (2 * DIN) + d;
        float x0 = 0.f, x1 = 0.f, x2 = 0.f;
        if (l0 >= 3) {
            x0 = bf2f(xp[(ptrdiff_t)(-3) * (2 * DIN)]);
            x1 = bf2f(xp[(ptrdiff_t)(-2) * (2 * DIN)]);
            x2 = bf2f(xp[(ptrdiff_t)(-1) * (2 * DIN)]);
        }
        #pragma unroll
        for (int t = 0; t < CT; ++t) {
            float x3 = bf2f(xp[(size_t)t * (2 * DIN)]);
            float a = fmaf(x0, w0, cbv);
            a = fmaf(x1, w1, a);
            a = fmaf(x2, w2, a);
            a = fmaf(x3, w3, a);
            float v = siluf(a);
            xcr[t] = v;
            As[t][d] = f2bf(v);
            x0 = x1; x1 = x2; x2 = x3;
        }
    }
    __syncthreads();

    // --- GEMM: Dbc[8][48] = As[8][512] @ W[48][512]^T (waves 0..2) ---
    {
        const int wave = tid >> 6;
        const int lane = tid & 63;
        const int m_l = lane & 15;
        const int q = lane >> 4;
        if (wave < 3) {
            float4v acc = (float4v)(0.f);
            for (int k0 = 0; k0 < DIN; k0 += 32) {
                short8 a  = *(const short8*)&As[m_l & (CT - 1)][k0 + q * 8];
                short8 bf = *(const short8*)(W + (size_t)(wave * 16 + m_l) * DIN + k0 + q * 8);
                acc = __builtin_amdgcn_mfma_f32_16x16x32_bf16(a, bf, acc, 0, 0, 0);
            }
            #pragma unroll
            for (int reg = 0; reg < 4; ++reg) {
                int row = q * 4 + reg;
                if (row < CT)
                    Dbc[row][wave * 16 + m_l] = acc[reg];
            }
        }
    }
    __syncthreads();

    // --- write dbc tile to global (consumed by scan_apply_out) ---
    for (int i = tid; i < CT * 48; i += 512) {
        int t = i / 48, col = i - t * 48;
        dbc[((size_t)(b * L_ + l0 + t)) * 48 + col] = Dbc[t][col];
    }

    // --- summary scan: 512 threads, each owns channel d ---
    float A[NST], tw[DTR];
    #pragma unroll
    for (int j = 0; j < NST; ++j) A[j] = -__expf(A_log[d * NST + j]);
    #pragma unroll
    for (int r = 0; r < DTR; ++r) tw[r] = dt_w[d * DTR + r];
    const float tb = dt_b[d];
    float h[NST];
    #pragma unroll
    for (int j = 0; j < NST; ++j) h[j] = 0.f;
    float ssum = 0.f;
    #pragma unroll
    for (int t = 0; t < CT; ++t) {
        float acc = tb;
        #pragma unroll
        for (int r = 0; r < DTR; ++r) acc = fmaf(Dbc[t][r], tw[r], acc);
        float dlt = softplusf(acc);
        float t0 = dlt * xcr[t];
        ssum += dlt;
        #pragma unroll
        for (int j = 0; j < NST; ++j) {
            float dA = __expf(A[j] * dlt);
            h[j] = fmaf(dA, h[j], t0 * Dbc[t][DTR + j]);
        }
    }
    S[((size_t)b * CHK + c) * DIN + d] = ssum;
    float* Hp = H + (((size_t)b * CHK + c) * NST) * DIN + d;
    #pragma unroll
    for (int j = 0; j < NST; ++j)
        Hp[(size_t)j * DIN] = h[j];
}

// ---- prefix over chunk summaries, in place: H[c] <- h_in(c) ----
__global__ __launch_bounds__(256) void scan_prefix_kernel(
    const float* __restrict__ S, float* __restrict__ H,
    const float* __restrict__ A_log)
{
    int idx = blockIdx.x * 256 + threadIdx.x;  // B*NST*DIN, d fastest
    int d = idx & (DIN - 1);
    int n = (idx >> 9) & (NST - 1);
    int b = idx >> 13;
    float A = -__expf(A_log[d * NST + n]);
    float hprev = 0.f;
    const float* Sp = S + (size_t)b * CHK * DIN + d;
    float* Hp = H + (((size_t)b * CHK) * NST + n) * DIN + d;
    for (int c = 0; c < CHK; ++c) {
        float Hc = Hp[(size_t)c * NST * DIN];
        float Sc = Sp[(size_t)c * DIN];
        Hp[(size_t)c * NST * DIN] = hprev;
        hprev = fmaf(__expf(A * Sc), hprev, Hc);
    }
}

// ---- fused scan apply + out_proj + residual + next-layer LN ----
// One chunk (8 rows) per block, 512 thr.
__global__ __launch_bounds__(512) void scan_apply_out(
    const float* __restrict__ dbc, const unsigned short* __restrict__ xz,
    const float* __restrict__ cw, const float* __restrict__ cb,
    const float* __restrict__ A_log, const float* __restrict__ dt_w,
    const float* __restrict__ dt_b, const float* __restrict__ Dskip,
    const float* __restrict__ H, const unsigned short* __restrict__ Wout,
    float* __restrict__ hbuf, const float* __restrict__ nlw,
    const float* __restrict__ nlb, unsigned short* __restrict__ ln16,
    float* __restrict__ chunkpartial, int last)
{
    __shared__ unsigned short Ys[CT][520];   // y bf16 (+8 pad)
    __shared__ float hrow[CT][264];          // h rows fp32 (+8 pad)
    const int tid = threadIdx.x;             // = channel d in phase A
    const int d = tid;
    const int c = blockIdx.x;
    const int b = blockIdx.y;
    const int l0 = c * CT;

    // --- phase A: scan apply (conv recomputed via rolling window) ---
    {
        float A[NST], tw[DTR];
        #pragma unroll
        for (int j = 0; j < NST; ++j) A[j] = -__expf(A_log[d * NST + j]);
        #pragma unroll
        for (int r = 0; r < DTR; ++r) tw[r] = dt_w[d * DTR + r];
        const float tb = dt_b[d];
        const float Dsk = Dskip[d];
        const float* bc = dbc + ((size_t)(b * L_ + l0)) * 48;
        const unsigned short* xp = xz + ((size_t)(b * L_ + l0)) * (2 * DIN) + d;
        const unsigned short* zp = xp + DIN;

        const float w0 = cw[d * 4 + 0], w1 = cw[d * 4 + 1];
        const float w2 = cw[d * 4 + 2], w3 = cw[d * 4 + 3];
        const float cbv = cb[d];
        float x0 = 0.f, x1 = 0.f, x2 = 0.f;
        if (l0 >= 3) {
            x0 = bf2f(xp[(ptrdiff_t)(-3) * (2 * DIN)]);
            x1 = bf2f(xp[(ptrdiff_t)(-2) * (2 * DIN)]);
            x2 = bf2f(xp[(ptrdiff_t)(-1) * (2 * DIN)]);
        }

        float h[NST];
        const float* Hp = H + (((size_t)b * CHK + c) * NST) * DIN + d;
        #pragma unroll
        for (int j = 0; j < NST; ++j) h[j] = Hp[(size_t)j * DIN];

        #pragma unroll
        for (int t = 0; t < CT; ++t) {
            float x3 = bf2f(xp[(size_t)t * (2 * DIN)]);
            float ca = fmaf(x0, w0, cbv);
            ca = fmaf(x1, w1, ca);
            ca = fmaf(x2, w2, ca);
            ca = fmaf(x3, w3, ca);
            float xcv = siluf(ca);
            x0 = x1; x1 = x2; x2 = x3;

            const float* br = bc + t * 48;    // block-uniform row
            float acc = tb;
            #pragma unroll
            for (int r = 0; r < DTR; ++r) acc = fmaf(br[r], tw[r], acc);
            float dlt = softplusf(acc);
            float zv  = bf2f(zp[(size_t)t * (2 * DIN)]);
            float t0 = dlt * xcv;
            float p = 0.f;
            #pragma unroll
            for (int j = 0; j < NST; ++j) {
                float dA = __expf(A[j] * dlt);
                h[j] = fmaf(dA, h[j], t0 * br[DTR + j]);
                p = fmaf(h[j], br[DTR + NST + j], p);
            }
            Ys[t][d] = f2bf((p + xcv * Dsk) * siluf(zv));
        }
    }
    __syncthreads();

    // --- load h_prev rows into LDS (8 rows x 64 lanes x 4 floats) ---
    {
        const int row = tid >> 6;
        const int col0 = (tid & 63) * 4;
        const float* hg = hbuf + ((size_t)(b * L_ + l0 + row)) * DM + col0;
        *(float4*)&hrow[row][col0] = *(const float4*)hg;
    }
    __syncthreads();

    // --- phase B: hrow += Ys @ Wout^T (8 waves x 2 n-tiles, disjoint cols) --
    // A-rows 8..15 clamped; their D rows discarded (row-separable).
    {
        const int wave = tid >> 6;
        const int lane = tid & 63;
        const int m_l = lane & 15;
        const int q = lane >> 4;
        #pragma unroll
        for (int nt = 0; nt < 2; ++nt) {
            const int n0 = (wave * 2 + nt) * 16;
            float4v acc;
            #pragma unroll
            for (int reg = 0; reg < 4; ++reg)
                acc[reg] = hrow[(q * 4 + reg) & (CT - 1)][n0 + m_l];
            for (int k0 = 0; k0 < DIN; k0 += 32) {
                short8 a = *(const short8*)&Ys[m_l & (CT - 1)][k0 + q * 8];
                short8 w = *(const short8*)(Wout + (size_t)(n0 + m_l) * DIN + k0 + q * 8);
                acc = __builtin_amdgcn_mfma_f32_16x16x32_bf16(a, w, acc, 0, 0, 0);
            }
            #pragma unroll
            for (int reg = 0; reg < 4; ++reg) {
                int row = q * 4 + reg;
                if (row < CT)
                    hrow[row][n0 + m_l] = acc[reg];
            }
        }
    }
    __syncthreads();

    // --- phase C ---
    if (!last) {
        // write h + LN with next layer's weights (8 rows x 64 lanes x 4 cols)
        const int row = tid >> 6;
        const int col0 = (tid & 63) * 4;
        float v[4];
        float s = 0.f, qq = 0.f;
        #pragma unroll
        for (int i = 0; i < 4; ++i) {
            v[i] = hrow[row][col0 + i];
            s += v[i];
            qq += v[i] * v[i];
        }
        s += __shfl_xor(s, 1);  qq += __shfl_xor(qq, 1);
        s += __shfl_xor(s, 2);  qq += __shfl_xor(qq, 2);
        s += __shfl_xor(s, 4);  qq += __shfl_xor(qq, 4);
        s += __shfl_xor(s, 8);  qq += __shfl_xor(qq, 8);
        s += __shfl_xor(s, 16); qq += __shfl_xor(qq, 16);
        s += __shfl_xor(s, 32); qq += __shfl_xor(qq, 32);
        float mu = s * (1.f / DM);
        float var = qq * (1.f / DM) - mu * mu;
        float rs = rsqrtf(var + 1e-5f);
        float* hg = hbuf + ((size_t)(b * L_ + l0 + row)) * DM + col0;
        *(float4*)hg = make_float4(v[0], v[1], v[2], v[3]);
        unsigned short* lo = ln16 + ((size_t)(b * L_ + l0 + row)) * DM + col0;
        #pragma unroll
        for (int i = 0; i < 4; ++i)
            lo[i] = f2bf((v[i] - mu) * rs * nlw[col0 + i] + nlb[col0 + i]);
    } else {
        // mean-pool partial: column sums of this chunk's 8 rows
        if (tid < DM) {
            float s = 0.f;
            #pragma unroll
            for (int t = 0; t < CT; ++t) s += hrow[t][tid];
            chunkpartial[((size_t)(b * CHK + c)) * DM + tid] = s;
        }
    }
}

// ---- head: reduce 128 chunk partials -> mean -> LN -> classifier ----
__global__ __launch_bounds__(256) void head_final_kernel(
    const float* __restrict__ chunkpartial, const float* __restrict__ fn_w,
    const float* __restrict__ fn_b, const float* __restrict__ cls_w,
    const float* __restrict__ cls_b, float* __restrict__ out)
{
    int b = blockIdx.x, t = threadIdx.x;
    const float* pp = chunkpartial + (size_t)b * CHK * DM + t;
    float s = 0.f;
    #pragma unroll 8
    for (int c = 0; c < CHK; ++c) s += pp[(size_t)c * DM];
    s *= (1.f / L_);
    float a = s, q = s * s;
    block_reduce2(a, q);
    float mu = a * (1.f / DM);
    float var = q * (1.f / DM) - mu * mu;
    float v = (s - mu) * rsqrtf(var + 1e-5f) * fn_w[t] + fn_b[t];
    __shared__ float pooled[DM];
    pooled[t] = v;
    __syncthreads();
    if (t < 10) {
        float acc = cls_b[t];
        for (int d2 = 0; d2 < DM; ++d2)
            acc = fmaf(pooled[d2], cls_w[t * DM + d2], acc);
        out[b * 10 + t] = acc;
    }
}

extern "C" void kernel_launch(void* const* d_in, const int* in_sizes, int n_in,
                              void* d_out, int out_size, void* d_ws, size_t ws_size,
                              hipStream_t stream)
{
    const float* x    = (const float*)d_in[0];
    const float* ipw  = (const float*)d_in[1];
    const float* ipb  = (const float*)d_in[2];
    const float* inw  = (const float*)d_in[3];
    const float* cw   = (const float*)d_in[4];
    const float* cb   = (const float*)d_in[5];
    const float* xpw  = (const float*)d_in[6];
    const float* dtw  = (const float*)d_in[7];
    const float* dtb  = (const float*)d_in[8];
    const float* alog = (const float*)d_in[9];
    const float* dsk  = (const float*)d_in[10];
    const float* opw  = (const float*)d_in[11];
    const float* lnw  = (const float*)d_in[12];
    const float* lnb  = (const float*)d_in[13];
    const float* fnw  = (const float*)d_in[14];
    const float* fnb  = (const float*)d_in[15];
    const float* clw  = (const float*)d_in[16];
    const float* clb  = (const float*)d_in[17];

    // workspace layout: fp32 region then bf16 region
    float* ws     = (float*)d_ws;
    float* hbuf   = ws;                                   // B*L*DM
    float* dbcbuf = hbuf   + (size_t)B_ * L_ * DM;        // B*L*48
    float* Sbuf   = dbcbuf + (size_t)B_ * L_ * 48;        // B*CHK*DIN
    float* Hbuf   = Sbuf   + (size_t)B_ * CHK * DIN;      // B*CHK*NST*DIN
    float* cpart  = Hbuf   + (size_t)B_ * CHK * NST * DIN;// B*CHK*DM
    float* tail   = cpart  + (size_t)B_ * CHK * DM;
    unsigned short* ln16  = (unsigned short*)tail;        // B*L*DM
    unsigned short* xz16  = ln16  + (size_t)B_ * L_ * DM; // B*L*2*DIN
    unsigned short* inw16 = xz16  + (size_t)B_ * L_ * 2 * DIN; // 4*1024*256
    unsigned short* xpw16 = inw16 + (size_t)4 * 1024 * DM;// 4*48*512
    unsigned short* opw16 = xpw16 + (size_t)4 * 48 * DIN; // 4*256*512

    const int BL = B_ * L_;                               // 4096
    const int NIN = 4 * 1024 * DM, NXP = 4 * 48 * DIN, NOP = 4 * DM * DIN;
    const int NCONV = (NIN + NXP + NOP + 255) / 256;

    prologue_kernel<<<NCONV + BL, 256, 0, stream>>>(
        inw, NIN, xpw, NXP, opw, NOP, inw16, xpw16, opw16, NCONV,
        x, ipw, ipb, lnw, lnb, hbuf, ln16);

    for (int i = 0; i < 4; ++i) {
        // xz(bf16) = ln16 @ in_w^T   [4096,1024]
        gemm_bt_bf16<<<dim3(2 * DIN / 64, BL / 64), 256, 0, stream>>>(
            ln16, inw16 + (size_t)i * 1024 * DM, xz16, BL, 2 * DIN, DM, DM);
        // conv+silu + x_proj + scan summary, fused per chunk (512 blocks)
        conv_xproj_summary<<<dim3(CHK, B_), 512, 0, stream>>>(
            xz16, cw + i * DIN * 4, cb + i * DIN,
            xpw16 + (size_t)i * 48 * DIN, alog + i * DIN * NST,
            dtw + i * DIN * DTR, dtb + i * DIN, dbcbuf, Sbuf, Hbuf);
        scan_prefix_kernel<<<B_ * NST * DIN / 256, 256, 0, stream>>>(
            Sbuf, Hbuf, alog + i * DIN * NST);
        // apply + out_proj + residual + next-layer LN (or pool partials)
        int last = (i == 3);
        const float* nlw = lnw + (last ? 0 : (i + 1) * DM);  // unused when last
        const float* nlb = lnb + (last ? 0 : (i + 1) * DM);
        scan_apply_out<<<dim3(CHK, B_), 512, 0, stream>>>(
            dbcbuf, xz16, cw + i * DIN * 4, cb + i * DIN,
            alog + i * DIN * NST, dtw + i * DIN * DTR, dtb + i * DIN,
            dsk + i * DIN, Hbuf, opw16 + (size_t)i * DM * DIN, hbuf,
            nlw, nlb, ln16, cpart, last);
    }

    head_final_kernel<<<B_, 256, 0, stream>>>(cpart, fnw, fnb, clw, clb,
                                              (float*)d_out);
}

// Round 17
// 383.856 us; speedup vs baseline: 1.0987x; 1.0987x over previous
//
#include <hip/hip_runtime.h>
#include <math.h>

#define B_ 4
#define L_ 1024
#define DM 256
#define DIN 512
#define NST 16
#define DTR 16
#define CHK 64          // number of chunks over L
#define CT (L_ / CHK)   // chunk length = 16

typedef short short8 __attribute__((ext_vector_type(8)));
typedef float float4v __attribute__((ext_vector_type(4)));

__device__ __forceinline__ float softplusf(float x) {
    return (x > 20.f) ? x : log1pf(__expf(x));
}
__device__ __forceinline__ float siluf(float x) {
    return x / (1.f + __expf(-x));
}
__device__ __forceinline__ unsigned short f2bf(float f) {  // RNE bf16
    unsigned int u = __float_as_uint(f);
    u = (u + 0x7fffu + ((u >> 16) & 1u)) >> 16;
    return (unsigned short)u;
}

// two-value block reduction (sum) over 256 threads = 4 waves
__device__ __forceinline__ void block_reduce2(float& a, float& q) {
    #pragma unroll
    for (int off = 32; off > 0; off >>= 1) {
        a += __shfl_down(a, off);
        q += __shfl_down(q, off);
    }
    __shared__ float sa[4], sq[4];
    int lane = threadIdx.x & 63, w = threadIdx.x >> 6;
    if (lane == 0) { sa[w] = a; sq[w] = q; }
    __syncthreads();
    a = sa[0] + sa[1] + sa[2] + sa[3];
    q = sq[0] + sq[1] + sq[2] + sq[3];
}

// ---- prologue: weight f2bf + input projection + layer-0 LN ----
__global__ __launch_bounds__(256) void prologue_kernel(
    const float* __restrict__ inw, int na, const float* __restrict__ xpw, int nb,
    const float* __restrict__ opw, int nc,
    unsigned short* __restrict__ oa, unsigned short* __restrict__ ob,
    unsigned short* __restrict__ oc, int nconv,
    const float* __restrict__ x, const float* __restrict__ ipw,
    const float* __restrict__ ipb, const float* __restrict__ lw0,
    const float* __restrict__ lb0, float* __restrict__ h0,
    unsigned short* __restrict__ ln16)
{
    if ((int)blockIdx.x < nconv) {
        int i = blockIdx.x * 256 + threadIdx.x;
        if (i < na) { oa[i] = f2bf(inw[i]); return; }
        int j = i - na;
        if (j < nb) { ob[j] = f2bf(xpw[j]); return; }
        int k = j - nb;
        if (k < nc) oc[k] = f2bf(opw[k]);
        return;
    }
    int row = blockIdx.x - nconv;                 // 0..4095 = b*L + l
    int l = row & (L_ - 1);
    int b = row >> 10;
    int d = threadIdx.x;
    const float* xb = x + (size_t)b * 3 * L_;
    float x0 = xb[l], x1 = xb[L_ + l], x2 = xb[2 * L_ + l];
    float acc = ipb[d];
    acc = fmaf(x0, ipw[d * 3 + 0], acc);
    acc = fmaf(x1, ipw[d * 3 + 1], acc);
    acc = fmaf(x2, ipw[d * 3 + 2], acc);
    float a = acc, q = acc * acc;
    block_reduce2(a, q);
    float mu = a * (1.f / DM);
    float var = q * (1.f / DM) - mu * mu;
    float rs = rsqrtf(var + 1e-5f);
    h0[(size_t)row * DM + d] = acc;
    ln16[(size_t)row * DM + d] = f2bf((acc - mu) * rs * lw0[d] + lb0[d]);
}

// ---- 64x64-tile bf16 MFMA GEMM (in_proj: C = A @ W^T, A = ln16) ----
__global__ __launch_bounds__(256) void gemm_bt_bf16(
    const unsigned short* __restrict__ A, const unsigned short* __restrict__ W,
    float* __restrict__ C, int M, int N, int K, int lda)
{
    __shared__ unsigned short As[64][72];
    __shared__ unsigned short Ws[64][72];
    const int tid = threadIdx.x;
    const int wave = tid >> 6;
    const int lane = tid & 63;
    const int m_l = lane & 15;
    const int q = lane >> 4;
    const int m0 = blockIdx.y * 64;
    const int n0 = blockIdx.x * 64;
    const int sr = tid >> 3;
    const int sc = (tid & 7) * 8;

    float4v acc[4];
    #pragma unroll
    for (int j = 0; j < 4; ++j) acc[j] = (float4v)(0.f);

    for (int k0 = 0; k0 < K; k0 += 64) {
        *(short8*)&As[sr][sc]      = *(const short8*)(A + (size_t)(m0 + sr) * lda + k0 + sc);
        *(short8*)&As[sr + 32][sc] = *(const short8*)(A + (size_t)(m0 + sr + 32) * lda + k0 + sc);
        *(short8*)&Ws[sr][sc]      = *(const short8*)(W + (size_t)(n0 + sr) * K + k0 + sc);
        *(short8*)&Ws[sr + 32][sc] = *(const short8*)(W + (size_t)(n0 + sr + 32) * K + k0 + sc);
        __syncthreads();
        #pragma unroll
        for (int kk = 0; kk < 64; kk += 32) {
            short8 a = *(const short8*)&As[wave * 16 + m_l][kk + q * 8];
            #pragma unroll
            for (int j4 = 0; j4 < 4; ++j4) {
                short8 bf = *(const short8*)&Ws[j4 * 16 + m_l][kk + q * 8];
                acc[j4] = __builtin_amdgcn_mfma_f32_16x16x32_bf16(a, bf, acc[j4], 0, 0, 0);
            }
        }
        __syncthreads();
    }
    #pragma unroll
    for (int j4 = 0; j4 < 4; ++j4) {
        int n = n0 + j4 * 16 + m_l;
        #pragma unroll
        for (int reg = 0; reg < 4; ++reg) {
            int m = m0 + wave * 16 + q * 4 + reg;
            C[(size_t)m * N + n] = acc[j4][reg];
        }
    }
}

// ---- fused conv+silu + x_proj GEMM + scan summary (one chunk per block) ----
__global__ __launch_bounds__(512) void conv_xproj_summary(
    const float* __restrict__ xz, const float* __restrict__ cw,
    const float* __restrict__ cb, const unsigned short* __restrict__ W,
    const float* __restrict__ A_log, const float* __restrict__ dt_w,
    const float* __restrict__ dt_b,
    float* __restrict__ dbc, float* __restrict__ S, float* __restrict__ H)
{
    __shared__ unsigned short As[CT][520];   // xc bf16, rows t, cols d (+8 pad)
    __shared__ float Dbc[CT][64];            // dbc tile (48 used)
    const int tid = threadIdx.x;             // 0..511, = channel d
    const int d = tid;
    const int c = blockIdx.x;
    const int b = blockIdx.y;
    const int l0 = c * CT;

    // --- conv + silu, rolling 4-tap window; keep fp32 in regs ---
    float xcr[CT];
    {
        const float w0 = cw[d * 4 + 0], w1 = cw[d * 4 + 1];
        const float w2 = cw[d * 4 + 2], w3 = cw[d * 4 + 3];
        const float cbv = cb[d];
        const float* xp = xz + ((size_t)(b * L_ + l0)) * (2 * DIN) + d;
        float x0 = 0.f, x1 = 0.f, x2 = 0.f;
        if (l0 >= 3) {
            x0 = xp[(ptrdiff_t)(-3) * (2 * DIN)];
            x1 = xp[(ptrdiff_t)(-2) * (2 * DIN)];
            x2 = xp[(ptrdiff_t)(-1) * (2 * DIN)];
        }
        #pragma unroll
        for (int t = 0; t < CT; ++t) {
            float x3 = xp[(size_t)t * (2 * DIN)];
            float a = fmaf(x0, w0, cbv);
            a = fmaf(x1, w1, a);
            a = fmaf(x2, w2, a);
            a = fmaf(x3, w3, a);
            float v = siluf(a);
            xcr[t] = v;
            As[t][d] = f2bf(v);
            x0 = x1; x1 = x2; x2 = x3;
        }
    }
    __syncthreads();

    // --- GEMM: Dbc[16][48] = As[16][512] @ W[48][512]^T (waves 0..2) ---
    {
        const int wave = tid >> 6;
        const int lane = tid & 63;
        const int m_l = lane & 15;
        const int q = lane >> 4;
        if (wave < 3) {
            float4v acc = (float4v)(0.f);
            for (int k0 = 0; k0 < DIN; k0 += 32) {
                short8 a  = *(const short8*)&As[m_l][k0 + q * 8];
                short8 bf = *(const short8*)(W + (size_t)(wave * 16 + m_l) * DIN + k0 + q * 8);
                acc = __builtin_amdgcn_mfma_f32_16x16x32_bf16(a, bf, acc, 0, 0, 0);
            }
            #pragma unroll
            for (int reg = 0; reg < 4; ++reg)
                Dbc[q * 4 + reg][wave * 16 + m_l] = acc[reg];
        }
    }
    __syncthreads();

    // --- write dbc tile to global (consumed by scan_apply_out) ---
    for (int i = tid; i < CT * 48; i += 512) {
        int t = i / 48, col = i - t * 48;
        dbc[((size_t)(b * L_ + l0 + t)) * 48 + col] = Dbc[t][col];
    }

    // --- summary scan: 512 threads, each owns channel d ---
    float A[NST], tw[DTR];
    #pragma unroll
    for (int j = 0; j < NST; ++j) A[j] = -__expf(A_log[d * NST + j]);
    #pragma unroll
    for (int r = 0; r < DTR; ++r) tw[r] = dt_w[d * DTR + r];
    const float tb = dt_b[d];
    float h[NST];
    #pragma unroll
    for (int j = 0; j < NST; ++j) h[j] = 0.f;
    float ssum = 0.f;
    #pragma unroll 4
    for (int t = 0; t < CT; ++t) {
        float acc = tb;
        #pragma unroll
        for (int r = 0; r < DTR; ++r) acc = fmaf(Dbc[t][r], tw[r], acc);
        float dlt = softplusf(acc);
        float t0 = dlt * xcr[t];
        ssum += dlt;
        #pragma unroll
        for (int j = 0; j < NST; ++j) {
            float dA = __expf(A[j] * dlt);
            h[j] = fmaf(dA, h[j], t0 * Dbc[t][DTR + j]);
        }
    }
    S[((size_t)b * CHK + c) * DIN + d] = ssum;
    float* Hp = H + (((size_t)b * CHK + c) * NST) * DIN + d;
    #pragma unroll
    for (int j = 0; j < NST; ++j)
        Hp[(size_t)j * DIN] = h[j];
}

// ---- prefix over chunk summaries, in place: H[c] <- h_in(c) ----
__global__ __launch_bounds__(256) void scan_prefix_kernel(
    const float* __restrict__ S, float* __restrict__ H,
    const float* __restrict__ A_log)
{
    int idx = blockIdx.x * 256 + threadIdx.x;  // B*NST*DIN, d fastest
    int d = idx & (DIN - 1);
    int n = (idx >> 9) & (NST - 1);
    int b = idx >> 13;
    float A = -__expf(A_log[d * NST + n]);
    float hprev = 0.f;
    const float* Sp = S + (size_t)b * CHK * DIN + d;
    float* Hp = H + (((size_t)b * CHK) * NST + n) * DIN + d;
    for (int c = 0; c < CHK; ++c) {
        float Hc = Hp[(size_t)c * NST * DIN];
        float Sc = Sp[(size_t)c * DIN];
        Hp[(size_t)c * NST * DIN] = hprev;
        hprev = fmaf(__expf(A * Sc), hprev, Hc);
    }
}

// ---- fused scan apply + out_proj + residual + next-layer LN ----
// One chunk (16 rows) per block, 512 thr.
__global__ __launch_bounds__(512) void scan_apply_out(
    const float* __restrict__ dbc, const float* __restrict__ xz,
    const float* __restrict__ cw, const float* __restrict__ cb,
    const float* __restrict__ A_log, const float* __restrict__ dt_w,
    const float* __restrict__ dt_b, const float* __restrict__ Dskip,
    const float* __restrict__ H, const unsigned short* __restrict__ Wout,
    float* __restrict__ hbuf, const float* __restrict__ nlw,
    const float* __restrict__ nlb, unsigned short* __restrict__ ln16,
    float* __restrict__ chunkpartial, int last)
{
    __shared__ unsigned short Ys[CT][520];   // y bf16 (+8 pad)
    __shared__ float hrow[CT][264];          // h rows fp32 (+8 pad)
    const int tid = threadIdx.x;             // = channel d in phase A
    const int d = tid;
    const int c = blockIdx.x;
    const int b = blockIdx.y;
    const int l0 = c * CT;

    // --- phase A: scan apply (conv recomputed via rolling window) ---
    {
        float A[NST], tw[DTR];
        #pragma unroll
        for (int j = 0; j < NST; ++j) A[j] = -__expf(A_log[d * NST + j]);
        #pragma unroll
        for (int r = 0; r < DTR; ++r) tw[r] = dt_w[d * DTR + r];
        const float tb = dt_b[d];
        const float Dsk = Dskip[d];
        const float* bc = dbc + ((size_t)(b * L_ + l0)) * 48;
        const float* xp = xz  + ((size_t)(b * L_ + l0)) * (2 * DIN) + d;
        const float* zp = xp + DIN;

        const float w0 = cw[d * 4 + 0], w1 = cw[d * 4 + 1];
        const float w2 = cw[d * 4 + 2], w3 = cw[d * 4 + 3];
        const float cbv = cb[d];
        float x0 = 0.f, x1 = 0.f, x2 = 0.f;
        if (l0 >= 3) {
            x0 = xp[(ptrdiff_t)(-3) * (2 * DIN)];
            x1 = xp[(ptrdiff_t)(-2) * (2 * DIN)];
            x2 = xp[(ptrdiff_t)(-1) * (2 * DIN)];
        }

        float h[NST];
        const float* Hp = H + (((size_t)b * CHK + c) * NST) * DIN + d;
        #pragma unroll
        for (int j = 0; j < NST; ++j) h[j] = Hp[(size_t)j * DIN];

        #pragma unroll 4
        for (int t = 0; t < CT; ++t) {
            float x3 = xp[(size_t)t * (2 * DIN)];
            float ca = fmaf(x0, w0, cbv);
            ca = fmaf(x1, w1, ca);
            ca = fmaf(x2, w2, ca);
            ca = fmaf(x3, w3, ca);
            float xcv = siluf(ca);
            x0 = x1; x1 = x2; x2 = x3;

            const float* br = bc + t * 48;    // block-uniform row
            float acc = tb;
            #pragma unroll
            for (int r = 0; r < DTR; ++r) acc = fmaf(br[r], tw[r], acc);
            float dlt = softplusf(acc);
            float zv  = zp[(size_t)t * (2 * DIN)];
            float t0 = dlt * xcv;
            float p = 0.f;
            #pragma unroll
            for (int j = 0; j < NST; ++j) {
                float dA = __expf(A[j] * dlt);
                h[j] = fmaf(dA, h[j], t0 * br[DTR + j]);
                p = fmaf(h[j], br[DTR + NST + j], p);
            }
            Ys[t][d] = f2bf((p + xcv * Dsk) * siluf(zv));
        }
    }
    __syncthreads();

    // --- load h_prev rows into LDS ---
    {
        const int row = tid >> 5;             // 16 rows x 32 threads
        const int col0 = (tid & 31) * 8;
        const float* hg = hbuf + ((size_t)(b * L_ + l0 + row)) * DM + col0;
        *(float4*)&hrow[row][col0]     = *(const float4*)hg;
        *(float4*)&hrow[row][col0 + 4] = *(const float4*)(hg + 4);
    }
    __syncthreads();

    // --- phase B: hrow += Ys @ Wout^T (8 waves x 2 n-tiles, disjoint cols) --
    {
        const int wave = tid >> 6;
        const int lane = tid & 63;
        const int m_l = lane & 15;
        const int q = lane >> 4;
        #pragma unroll
        for (int nt = 0; nt < 2; ++nt) {
            const int n0 = (wave * 2 + nt) * 16;
            float4v acc;
            #pragma unroll
            for (int reg = 0; reg < 4; ++reg)
                acc[reg] = hrow[q * 4 + reg][n0 + m_l];
            for (int k0 = 0; k0 < DIN; k0 += 32) {
                short8 a = *(const short8*)&Ys[m_l][k0 + q * 8];
                short8 w = *(const short8*)(Wout + (size_t)(n0 + m_l) * DIN + k0 + q * 8);
                acc = __builtin_amdgcn_mfma_f32_16x16x32_bf16(a, w, acc, 0, 0, 0);
            }
            #pragma unroll
            for (int reg = 0; reg < 4; ++reg)
                hrow[q * 4 + reg][n0 + m_l] = acc[reg];
        }
    }
    __syncthreads();

    // --- phase C ---
    if (!last) {
        // write h + LN with next layer's weights
        const int row = tid >> 5;
        const int col0 = (tid & 31) * 8;
        float v[8];
        float s = 0.f, qq = 0.f;
        #pragma unroll
        for (int i = 0; i < 8; ++i) {
            v[i] = hrow[row][col0 + i];
            s += v[i];
            qq += v[i] * v[i];
        }
        s += __shfl_xor(s, 1);  qq += __shfl_xor(qq, 1);
        s += __shfl_xor(s, 2);  qq += __shfl_xor(qq, 2);
        s += __shfl_xor(s, 4);  qq += __shfl_xor(qq, 4);
        s += __shfl_xor(s, 8);  qq += __shfl_xor(qq, 8);
        s += __shfl_xor(s, 16); qq += __shfl_xor(qq, 16);
        float mu = s * (1.f / DM);
        float var = qq * (1.f / DM) - mu * mu;
        float rs = rsqrtf(var + 1e-5f);
        float* hg = hbuf + ((size_t)(b * L_ + l0 + row)) * DM + col0;
        *(float4*)hg       = make_float4(v[0], v[1], v[2], v[3]);
        *(float4*)(hg + 4) = make_float4(v[4], v[5], v[6], v[7]);
        unsigned short* lo = ln16 + ((size_t)(b * L_ + l0 + row)) * DM + col0;
        #pragma unroll
        for (int i = 0; i < 8; ++i)
            lo[i] = f2bf((v[i] - mu) * rs * nlw[col0 + i] + nlb[col0 + i]);
    } else {
        // mean-pool partial: column sums of this chunk's 16 rows
        if (tid < DM) {
            float s = 0.f;
            #pragma unroll
            for (int t = 0; t < CT; ++t) s += hrow[t][tid];
            chunkpartial[((size_t)(b * CHK + c)) * DM + tid] = s;
        }
    }
}

// ---- head: reduce 64 chunk partials -> mean -> LN -> classifier ----
__global__ __launch_bounds__(256) void head_final_kernel(
    const float* __restrict__ chunkpartial, const float* __restrict__ fn_w,
    const float* __restrict__ fn_b, const float* __restrict__ cls_w,
    const float* __restrict__ cls_b, float* __restrict__ out)
{
    int b = blockIdx.x, t = threadIdx.x;
    const float* pp = chunkpartial + (size_t)b * CHK * DM + t;
    float s = 0.f;
    #pragma unroll 8
    for (int c = 0; c < CHK; ++c) s += pp[(size_t)c * DM];
    s *= (1.f / L_);
    float a = s, q = s * s;
    block_reduce2(a, q);
    float mu = a * (1.f / DM);
    float var = q * (1.f / DM) - mu * mu;
    float v = (s - mu) * rsqrtf(var + 1e-5f) * fn_w[t] + fn_b[t];
    __shared__ float pooled[DM];
    pooled[t] = v;
    __syncthreads();
    if (t < 10) {
        float acc = cls_b[t];
        for (int d2 = 0; d2 < DM; ++d2)
            acc = fmaf(pooled[d2], cls_w[t * DM + d2], acc);
        out[b * 10 + t] = acc;
    }
}

extern "C" void kernel_launch(void* const* d_in, const int* in_sizes, int n_in,
                              void* d_out, int out_size, void* d_ws, size_t ws_size,
                              hipStream_t stream)
{
    const float* x    = (const float*)d_in[0];
    const float* ipw  = (const float*)d_in[1];
    const float* ipb  = (const float*)d_in[2];
    const float* inw  = (const float*)d_in[3];
    const float* cw   = (const float*)d_in[4];
    const float* cb   = (const float*)d_in[5];
    const float* xpw  = (const float*)d_in[6];
    const float* dtw  = (const float*)d_in[7];
    const float* dtb  = (const float*)d_in[8];
    const float* alog = (const float*)d_in[9];
    const float* dsk  = (const float*)d_in[10];
    const float* opw  = (const float*)d_in[11];
    const float* lnw  = (const float*)d_in[12];
    const float* lnb  = (const float*)d_in[13];
    const float* fnw  = (const float*)d_in[14];
    const float* fnb  = (const float*)d_in[15];
    const float* clw  = (const float*)d_in[16];
    const float* clb  = (const float*)d_in[17];

    // workspace layout (float units)
    float* ws     = (float*)d_ws;
    float* hbuf   = ws;                                   // B*L*DM
    float* xzbuf  = hbuf   + (size_t)B_ * L_ * DM;        // B*L*2*DIN
    float* dbcbuf = xzbuf  + (size_t)B_ * L_ * 2 * DIN;   // B*L*48
    float* Sbuf   = dbcbuf + (size_t)B_ * L_ * 48;        // B*CHK*DIN
    float* Hbuf   = Sbuf   + (size_t)B_ * CHK * DIN;      // B*CHK*NST*DIN
    float* cpart  = Hbuf   + (size_t)B_ * CHK * NST * DIN;// B*CHK*DM
    float* tail   = cpart  + (size_t)B_ * CHK * DM;
    unsigned short* ln16  = (unsigned short*)tail;        // B*L*DM
    unsigned short* inw16 = ln16  + (size_t)B_ * L_ * DM; // 4*1024*256
    unsigned short* xpw16 = inw16 + (size_t)4 * 1024 * DM;// 4*48*512
    unsigned short* opw16 = xpw16 + (size_t)4 * 48 * DIN; // 4*256*512

    const int BL = B_ * L_;                               // 4096
    const int NIN = 4 * 1024 * DM, NXP = 4 * 48 * DIN, NOP = 4 * DM * DIN;
    const int NCONV = (NIN + NXP + NOP + 255) / 256;

    prologue_kernel<<<NCONV + BL, 256, 0, stream>>>(
        inw, NIN, xpw, NXP, opw, NOP, inw16, xpw16, opw16, NCONV,
        x, ipw, ipb, lnw, lnb, hbuf, ln16);

    for (int i = 0; i < 4; ++i) {
        // xz = ln16 @ in_w^T   [4096,1024] (pure GEMM; LN already done)
        gemm_bt_bf16<<<dim3(2 * DIN / 64, BL / 64), 256, 0, stream>>>(
            ln16, inw16 + (size_t)i * 1024 * DM, xzbuf, BL, 2 * DIN, DM, DM);
        // conv+silu + x_proj + scan summary, fused per chunk
        conv_xproj_summary<<<dim3(CHK, B_), 512, 0, stream>>>(
            xzbuf, cw + i * DIN * 4, cb + i * DIN,
            xpw16 + (size_t)i * 48 * DIN, alog + i * DIN * NST,
            dtw + i * DIN * DTR, dtb + i * DIN, dbcbuf, Sbuf, Hbuf);
        scan_prefix_kernel<<<B_ * NST * DIN / 256, 256, 0, stream>>>(
            Sbuf, Hbuf, alog + i * DIN * NST);
        // apply + out_proj + residual + next-layer LN (or pool partials)
        int last = (i == 3);
        const float* nlw = lnw + (last ? 0 : (i + 1) * DM);  // unused when last
        const float* nlb = lnb + (last ? 0 : (i + 1) * DM);
        scan_apply_out<<<dim3(CHK, B_), 512, 0, stream>>>(
            dbcbuf, xzbuf, cw + i * DIN * 4, cb + i * DIN,
            alog + i * DIN * NST, dtw + i * DIN * DTR, dtb + i * DIN,
            dsk + i * DIN, Hbuf, opw16 + (size_t)i * DM * DIN, hbuf,
            nlw, nlb, ln16, cpart, last);
    }

    head_final_kernel<<<B_, 256, 0, stream>>>(cpart, fnw, fnb, clw, clb,
                                              (float*)d_out);
}